// Round 2
// baseline (4387.682 us; speedup 1.0000x reference)
//
#include <hip/hip_runtime.h>
#include <hip/hip_bf16.h>
#include <math.h>

#define D_MODEL   2048
#define D_INNER   4096
#define NHEADS    64
#define HEAD_DIM  64
#define D_STATE   128
#define CHUNK     256
#define CONV_DIM  (D_INNER + 2*D_STATE)            // 4352
#define D_IN_PROJ (2*D_INNER + 2*D_STATE + NHEADS) // 8512
#define BATCH     2
#define SEQ       2048
#define NCHUNK    (SEQ/CHUNK)                      // 8
#define EPS_RMS   1e-5f

typedef unsigned short u16;
typedef __attribute__((ext_vector_type(8))) unsigned short u16x8;
typedef __attribute__((ext_vector_type(4))) unsigned short u16x4;

__device__ __forceinline__ float us2f(u16 u){
    union { unsigned int i; float f; } c; c.i = ((unsigned int)u) << 16; return c.f;
}
__device__ __forceinline__ u16 f2us(float f){
    union { float f; unsigned int i; } c; c.f = f;
    unsigned int r = c.i + 0x7FFFu + ((c.i >> 16) & 1u);
    return (u16)(r >> 16);
}
__device__ __forceinline__ float siluf(float x){ return x / (1.f + expf(-x)); }

// ---------------- GEMM: C[M,N] = A[M,K] @ B[K,N], row-major, templated dtypes ----------------
// BM=128, BN=64, BK=16, 256 threads, 8x4 per thread.
template<typename TA, typename TB, typename TC>
__global__ __launch_bounds__(256)
void gemm_tmpl(const TA* __restrict__ A, const TB* __restrict__ B,
               TC* __restrict__ C, int M, int N, int K)
{
    __shared__ float Ast[16][128];  // Ast[k][m]
    __shared__ float Bs[16][64];
    const int t  = threadIdx.x;
    const int m0 = blockIdx.y * 128;
    const int n0 = blockIdx.x * 64;
    const int arow = t >> 1, ak = (t & 1) * 8;
    const int brow = t >> 4, bcol = (t & 15) * 4;
    const int ty = t >> 4, tx = t & 15;

    float acc[8][4];
    #pragma unroll
    for (int i = 0; i < 8; i++)
        #pragma unroll
        for (int j = 0; j < 4; j++) acc[i][j] = 0.f;

    for (int k0 = 0; k0 < K; k0 += 16) {
        float a8[8], b4[4];
        {
            const TA* ap = &A[(size_t)(m0 + arow) * K + k0 + ak];
            if constexpr (sizeof(TA) == 4) {
                float4 a0 = *(const float4*)ap;
                float4 a1 = *(const float4*)(ap + 4);
                a8[0]=a0.x; a8[1]=a0.y; a8[2]=a0.z; a8[3]=a0.w;
                a8[4]=a1.x; a8[5]=a1.y; a8[6]=a1.z; a8[7]=a1.w;
            } else {
                u16x8 v = *(const u16x8*)ap;
                #pragma unroll
                for (int i = 0; i < 8; i++) a8[i] = us2f(v[i]);
            }
        }
        {
            const TB* bp = &B[(size_t)(k0 + brow) * N + n0 + bcol];
            if constexpr (sizeof(TB) == 4) {
                float4 v = *(const float4*)bp;
                b4[0]=v.x; b4[1]=v.y; b4[2]=v.z; b4[3]=v.w;
            } else {
                u16x4 v = *(const u16x4*)bp;
                #pragma unroll
                for (int i = 0; i < 4; i++) b4[i] = us2f(v[i]);
            }
        }
        __syncthreads();
        #pragma unroll
        for (int i = 0; i < 8; i++) Ast[ak + i][arow] = a8[i];
        *(float4*)&Bs[brow][bcol] = make_float4(b4[0], b4[1], b4[2], b4[3]);
        __syncthreads();
        #pragma unroll
        for (int kk = 0; kk < 16; kk++) {
            float4 av0 = *(const float4*)&Ast[kk][ty*8];
            float4 av1 = *(const float4*)&Ast[kk][ty*8 + 4];
            float4 bv2 = *(const float4*)&Bs[kk][tx*4];
            float a[8] = {av0.x, av0.y, av0.z, av0.w, av1.x, av1.y, av1.z, av1.w};
            float b[4] = {bv2.x, bv2.y, bv2.z, bv2.w};
            #pragma unroll
            for (int i = 0; i < 8; i++)
                #pragma unroll
                for (int j = 0; j < 4; j++)
                    acc[i][j] += a[i] * b[j];
        }
    }
    #pragma unroll
    for (int i = 0; i < 8; i++) {
        TC* cp = &C[(size_t)(m0 + ty*8 + i) * N + n0 + tx*4];
        if constexpr (sizeof(TC) == 4) {
            *(float4*)cp = make_float4(acc[i][0], acc[i][1], acc[i][2], acc[i][3]);
        } else {
            u16x4 v;
            v[0]=f2us(acc[i][0]); v[1]=f2us(acc[i][1]);
            v[2]=f2us(acc[i][2]); v[3]=f2us(acc[i][3]);
            *(u16x4*)cp = v;
        }
    }
}

// ---------------- conv1d (K=4) + bias + SiLU, split into x / B / C (bf16 io) ----------------
__global__ __launch_bounds__(256)
void conv_silu(const u16* __restrict__ zx, const float* __restrict__ cw,
               const float* __restrict__ cb, u16* __restrict__ xconv,
               u16* __restrict__ Bbuf, u16* __restrict__ Cbuf)
{
    int idx = blockIdx.x * 256 + threadIdx.x;       // < BATCH*SEQ*CONV_DIM
    int c = idx % CONV_DIM;
    int r = idx / CONV_DIM;                          // b*SEQ + l
    int l = r & (SEQ - 1);
    float y = cb[c];
    #pragma unroll
    for (int k = 0; k < 4; k++) {
        int ls = l + k - 3;
        if (ls >= 0)
            y += us2f(zx[(size_t)(r + k - 3) * D_IN_PROJ + D_INNER + c]) * cw[c*4 + k];
    }
    y = y / (1.f + expf(-y));
    u16 yb = f2us(y);
    if (c < D_INNER)                xconv[(size_t)r * D_INNER + c] = yb;
    else if (c < D_INNER + D_STATE) Bbuf[(size_t)r * D_STATE + (c - D_INNER)] = yb;
    else                            Cbuf[(size_t)r * D_STATE + (c - D_INNER - D_STATE)] = yb;
}

// ---------------- dt softplus + per-chunk cumsum of dA ----------------
__global__ __launch_bounds__(256)
void dt_acs(const u16* __restrict__ zx, const float* __restrict__ Aparam,
            const float* __restrict__ dt_bias, float* __restrict__ dtT,
            float* __restrict__ Acs)
{
    __shared__ float sb[CHUNK];
    int blk = blockIdx.x;                 // b*512 + h*8 + c
    int c = blk & 7, h = (blk >> 3) & 63, b = blk >> 9;
    int t = threadIdx.x;
    int lg = c * CHUNK + t;
    int row = b * SEQ + lg;
    float x = us2f(zx[(size_t)row * D_IN_PROJ + (2*D_INNER + 2*D_STATE) + h]) + dt_bias[h];
    float dt = (x > 20.f) ? x : log1pf(expf(x));
    float v = dt * Aparam[h];
    sb[t] = v; __syncthreads();
    #pragma unroll
    for (int off = 1; off < 256; off <<= 1) {
        float add = (t >= off) ? sb[t - off] : 0.f;
        __syncthreads();
        v += add; sb[t] = v;
        __syncthreads();
    }
    int o = (b * NHEADS + h) * SEQ + lg;
    dtT[o] = dt;
    Acs[o] = v;
}

// ---------------- per-chunk states: states[b,c,h,p,n] (f32 out) ----------------
__global__ __launch_bounds__(256)
void chunk_states(const u16* __restrict__ xconv, const u16* __restrict__ Bbuf,
                  const float* __restrict__ dtT, const float* __restrict__ Acs,
                  float* __restrict__ states)
{
    __shared__ float Bsh[16][128];
    __shared__ float xsh[16][64];
    __shared__ float wsh[16];
    int blk = blockIdx.x;                 // b*512 + c*64 + h
    int h = blk & 63, c = (blk >> 6) & 7, b = blk >> 9;
    int t = threadIdx.x;
    int n = t & 127, p0 = (t >> 7) * 32;
    int bh = b * NHEADS + h;
    float acs_last = Acs[(size_t)bh * SEQ + c * CHUNK + 255];

    float acc[32];
    #pragma unroll
    for (int i = 0; i < 32; i++) acc[i] = 0.f;

    for (int l0 = 0; l0 < CHUNK; l0 += 16) {
        __syncthreads();
        {
            int lr = t >> 4, nc = (t & 15) * 8;
            u16x8 v = *(const u16x8*)&Bbuf[(size_t)(b*SEQ + c*CHUNK + l0 + lr) * D_STATE + nc];
            #pragma unroll
            for (int q = 0; q < 8; q++) Bsh[lr][nc + q] = us2f(v[q]);
        }
        {
            int lr = t >> 4, pc = (t & 15) * 4;
            u16x4 v = *(const u16x4*)&xconv[(size_t)(b*SEQ + c*CHUNK + l0 + lr) * D_INNER + h*HEAD_DIM + pc];
            #pragma unroll
            for (int q = 0; q < 4; q++) xsh[lr][pc + q] = us2f(v[q]);
        }
        if (t < 16) {
            int lgi = c * CHUNK + l0 + t;
            float dt = dtT[(size_t)bh * SEQ + lgi];
            float a  = Acs[(size_t)bh * SEQ + lgi];
            wsh[t] = dt * expf(acs_last - a);
        }
        __syncthreads();
        #pragma unroll
        for (int lr = 0; lr < 16; lr++) {
            float bw = Bsh[lr][n] * wsh[lr];
            #pragma unroll
            for (int i = 0; i < 32; i++) acc[i] += bw * xsh[lr][p0 + i];
        }
    }
    size_t base = ((size_t)((b*NCHUNK + c)*NHEADS + h)) * (HEAD_DIM * D_STATE);
    #pragma unroll
    for (int i = 0; i < 32; i++)
        states[base + (size_t)(p0 + i) * D_STATE + n] = acc[i];
}

// ---------------- inter-chunk recurrence, in place ----------------
__global__ __launch_bounds__(256)
void state_recurrence(float* __restrict__ states, const float* __restrict__ Acs)
{
    int idx = blockIdx.x * 256 + threadIdx.x;  // < BATCH*NHEADS*8192
    int pn = idx & 8191;
    int bh = idx >> 13;
    int b = bh >> 6, h = bh & 63;
    float E = 0.f;
    for (int c = 0; c < NCHUNK; c++) {
        size_t off = ((size_t)((b*NCHUNK + c)*NHEADS + h)) * 8192 + pn;
        float s = states[off];
        states[off] = E;
        float cs = Acs[(size_t)(b*NHEADS + h) * SEQ + c*CHUNK + 255];
        E = expf(cs) * E + s;
    }
}

// ---------------- chunk output: Y = Y_off + D*x + Y_diag (bf16 out) ----------------
__global__ __launch_bounds__(256)
void chunk_output(const u16* __restrict__ xconv, const u16* __restrict__ Bbuf,
                  const u16* __restrict__ Cbuf, const float* __restrict__ dtT,
                  const float* __restrict__ Acs, const float* __restrict__ states,
                  const float* __restrict__ Dparam, u16* __restrict__ Y)
{
    __shared__ float prev[64][128];  // 32 KB
    __shared__ float Bsh[32][128];   // 16 KB
    __shared__ float xsh[32][64];    // 8 KB
    __shared__ float wsh[32];
    __shared__ float ash[32];
    int blk = blockIdx.x;            // b*512 + c*64 + h
    int h = blk & 63, c = (blk >> 6) & 7, b = blk >> 9;
    int t = threadIdx.x;             // = l within chunk
    int bh = b * NHEADS + h;
    int lg = c * CHUNK + t;

    {
        size_t base = ((size_t)((b*NCHUNK + c)*NHEADS + h)) * 8192;
        for (int i = t*4; i < 8192; i += 1024)
            *(float4*)&prev[0][i] = *(const float4*)&states[base + i];
    }
    float cl[128];
    {
        const u16x8* src = (const u16x8*)&Cbuf[(size_t)(b*SEQ + lg) * D_STATE];
        #pragma unroll
        for (int i = 0; i < 16; i++) {
            u16x8 v = src[i];
            #pragma unroll
            for (int q = 0; q < 8; q++) cl[i*8 + q] = us2f(v[q]);
        }
    }
    float acs_l = Acs[(size_t)bh * SEQ + lg];
    float el = expf(acs_l);
    float Dh = Dparam[h];
    float acc[64];
    __syncthreads();
    // Y_off = el * C_l . prev[p,:]
    #pragma unroll
    for (int p = 0; p < 64; p++) {
        float dot = 0.f;
        #pragma unroll
        for (int nn = 0; nn < 128; nn++) dot += cl[nn] * prev[p][nn];
        acc[p] = el * dot;
    }
    // D skip
    {
        const u16x8* xsrc = (const u16x8*)&xconv[(size_t)(b*SEQ + lg) * D_INNER + h*HEAD_DIM];
        #pragma unroll
        for (int p8 = 0; p8 < 8; p8++) {
            u16x8 v = xsrc[p8];
            #pragma unroll
            for (int q = 0; q < 8; q++) acc[p8*8 + q] += Dh * us2f(v[q]);
        }
    }
    // diagonal (triangular) part, s-tiles of 32
    for (int st = 0; st < 8; st++) {
        __syncthreads();
        {
            int lr = t >> 3, nc = (t & 7) * 16;
            const u16* src = &Bbuf[(size_t)(b*SEQ + c*CHUNK + st*32 + lr) * D_STATE + nc];
            u16x8 v0 = *(const u16x8*)&src[0];
            u16x8 v1 = *(const u16x8*)&src[8];
            #pragma unroll
            for (int q = 0; q < 8; q++) { Bsh[lr][nc + q] = us2f(v0[q]); Bsh[lr][nc + 8 + q] = us2f(v1[q]); }
        }
        {
            int lr = t >> 3, pc = (t & 7) * 8;
            u16x8 v = *(const u16x8*)&xconv[(size_t)(b*SEQ + c*CHUNK + st*32 + lr) * D_INNER + h*HEAD_DIM + pc];
            #pragma unroll
            for (int q = 0; q < 8; q++) xsh[lr][pc + q] = us2f(v[q]);
        }
        if (t < 32) {
            int sg = c*CHUNK + st*32 + t;
            wsh[t] = dtT[(size_t)bh * SEQ + sg];
            ash[t] = Acs[(size_t)bh * SEQ + sg];
        }
        __syncthreads();
        if (st*32 > t) continue;
        int smax = t - st*32 + 1; if (smax > 32) smax = 32;
        for (int ss = 0; ss < smax; ss++) {
            float g = 0.f;
            #pragma unroll
            for (int nn = 0; nn < 128; nn++) g += cl[nn] * Bsh[ss][nn];
            float w = expf(acs_l - ash[ss]) * wsh[ss] * g;
            #pragma unroll
            for (int p = 0; p < 64; p++) acc[p] += w * xsh[ss][p];
        }
    }
    u16* dst = &Y[(size_t)(b*SEQ + lg) * D_INNER + h*HEAD_DIM];
    #pragma unroll
    for (int p8 = 0; p8 < 8; p8++) {
        u16x8 v;
        #pragma unroll
        for (int q = 0; q < 8; q++) v[q] = f2us(acc[p8*8 + q]);
        *(u16x8*)&dst[p8*8] = v;
    }
}

// ---------------- gated RMSNorm (NGROUPS=1), in place on Y (bf16) ----------------
__global__ __launch_bounds__(256)
void gated_rmsnorm_k(u16* __restrict__ Y, const u16* __restrict__ zx,
                     const float* __restrict__ nw)
{
    __shared__ float xs[D_INNER];
    __shared__ float red[8];
    int row = blockIdx.x;
    int t = threadIdx.x;
    float ss = 0.f;
    for (int i = t*8; i < D_INNER; i += 2048) {
        u16x8 yv = *(const u16x8*)&Y[(size_t)row * D_INNER + i];
        u16x8 zv = *(const u16x8*)&zx[(size_t)row * D_IN_PROJ + i];
        #pragma unroll
        for (int q = 0; q < 8; q++) {
            float x = us2f(yv[q]) * siluf(us2f(zv[q]));
            xs[i + q] = x;
            ss += x * x;
        }
    }
    #pragma unroll
    for (int off = 32; off > 0; off >>= 1) ss += __shfl_down(ss, off);
    int wid = t >> 6, lane = t & 63;
    if (lane == 0) red[wid] = ss;
    __syncthreads();
    if (t == 0) {
        float tot = red[0] + red[1] + red[2] + red[3];
        red[0] = rsqrtf(tot / (float)D_INNER + EPS_RMS);
    }
    __syncthreads();
    float sc = red[0];
    for (int i = t*8; i < D_INNER; i += 2048) {
        u16x8 o;
        #pragma unroll
        for (int q = 0; q < 8; q++) o[q] = f2us(xs[i + q] * sc * nw[i + q]);
        *(u16x8*)&Y[(size_t)row * D_INNER + i] = o;
    }
}

__global__ void ws_fail_k(float* out){ out[threadIdx.x] = 1.0e6f; }

// ---------------- launch ----------------
extern "C" void kernel_launch(void* const* d_in, const int* in_sizes, int n_in,
                              void* d_out, int out_size, void* d_ws, size_t ws_size,
                              hipStream_t stream)
{
    const float* hidden  = (const float*)d_in[0];
    const float* W_in    = (const float*)d_in[1];
    const float* conv_w  = (const float*)d_in[2];
    const float* conv_b  = (const float*)d_in[3];
    const float* Aparam  = (const float*)d_in[4];
    const float* Dparam  = (const float*)d_in[5];
    const float* dt_bias = (const float*)d_in[6];
    const float* norm_w  = (const float*)d_in[7];
    const float* W_out   = (const float*)d_in[8];
    float* out = (float*)d_out;

    const int M = BATCH * SEQ;  // 4096

    size_t off = 0;
    char* wsb = (char*)d_ws;
    u16*   zx     = (u16*)  (wsb + off); off += (size_t)M * D_IN_PROJ * 2;           // 69.7 MB
    u16*   xconv  = (u16*)  (wsb + off); off += (size_t)M * D_INNER * 2;             // 33.5 MB
    u16*   Bbuf   = (u16*)  (wsb + off); off += (size_t)M * D_STATE * 2;             // 1 MB
    u16*   Cbuf   = (u16*)  (wsb + off); off += (size_t)M * D_STATE * 2;             // 1 MB
    float* dtT    = (float*)(wsb + off); off += (size_t)BATCH * NHEADS * SEQ * 4;    // 1 MB
    float* Acs    = (float*)(wsb + off); off += (size_t)BATCH * NHEADS * SEQ * 4;    // 1 MB
    float* states = (float*)(wsb + off); off += (size_t)BATCH * NCHUNK * NHEADS * HEAD_DIM * D_STATE * 4; // 33.5 MB
    u16*   Ybuf   = (u16*)  (wsb + off); off += (size_t)M * D_INNER * 2;             // 33.5 MB

    if (off > ws_size) {            // scratch too small: emit sentinel instead of faulting
        ws_fail_k<<<1, 64, 0, stream>>>(out);
        return;
    }

    gemm_tmpl<float, float, u16><<<dim3(D_IN_PROJ/64, M/128), 256, 0, stream>>>(hidden, W_in, zx, M, D_IN_PROJ, D_MODEL);
    conv_silu<<<(M * CONV_DIM) / 256, 256, 0, stream>>>(zx, conv_w, conv_b, xconv, Bbuf, Cbuf);
    dt_acs<<<BATCH * NHEADS * NCHUNK, 256, 0, stream>>>(zx, Aparam, dt_bias, dtT, Acs);
    chunk_states<<<BATCH * NCHUNK * NHEADS, 256, 0, stream>>>(xconv, Bbuf, dtT, Acs, states);
    state_recurrence<<<(BATCH * NHEADS * HEAD_DIM * D_STATE) / 256, 256, 0, stream>>>(states, Acs);
    chunk_output<<<BATCH * NCHUNK * NHEADS, 256, 0, stream>>>(xconv, Bbuf, Cbuf, dtT, Acs, states, Dparam, Ybuf);
    gated_rmsnorm_k<<<M, 256, 0, stream>>>(Ybuf, zx, norm_w);
    gemm_tmpl<u16, float, float><<<dim3(D_MODEL/64, M/128), 256, 0, stream>>>(Ybuf, W_out, out, M, D_MODEL, D_INNER);
}

// Round 3
// 2078.175 us; speedup vs baseline: 2.1113x; 2.1113x over previous
//
#include <hip/hip_runtime.h>
#include <hip/hip_bf16.h>
#include <math.h>

#define D_MODEL   2048
#define D_INNER   4096
#define NHEADS    64
#define HEAD_DIM  64
#define D_STATE   128
#define CHUNK     256
#define CONV_DIM  (D_INNER + 2*D_STATE)            // 4352
#define D_IN_PROJ (2*D_INNER + 2*D_STATE + NHEADS) // 8512
#define LD_ZX     8576                             // D_IN_PROJ padded to 128
#define BATCH     2
#define SEQ       2048
#define NCHUNK    (SEQ/CHUNK)                      // 8
#define EPS_RMS   1e-5f

typedef unsigned short u16;
typedef __attribute__((ext_vector_type(8))) unsigned short u16x8;
typedef __attribute__((ext_vector_type(4))) unsigned short u16x4;
typedef __attribute__((ext_vector_type(8))) short bf16x8;   // MFMA A/B frag (8 bf16)
typedef __attribute__((ext_vector_type(4))) float f32x4;    // MFMA C/D frag

__device__ __forceinline__ float us2f(u16 u){
    union { unsigned int i; float f; } c; c.i = ((unsigned int)u) << 16; return c.f;
}
__device__ __forceinline__ u16 f2us(float f){
    union { float f; unsigned int i; } c; c.f = f;
    unsigned int r = c.i + 0x7FFFu + ((c.i >> 16) & 1u);
    return (u16)(r >> 16);
}
__device__ __forceinline__ float siluf(float x){ return x / (1.f + expf(-x)); }

__device__ __forceinline__ void gload_lds16(const void* g, void* l) {
    __builtin_amdgcn_global_load_lds((const __attribute__((address_space(1))) void*)g,
                                     (__attribute__((address_space(3))) void*)l, 16, 0, 0);
}

// ---------- elementwise f32 -> bf16 ----------
__global__ __launch_bounds__(256)
void cvt_bf16(const float* __restrict__ in, u16* __restrict__ out, int n4)
{
    int i = blockIdx.x * 256 + threadIdx.x;
    if (i >= n4) return;
    float4 v = *(const float4*)&in[(size_t)i * 4];
    u16x4 o; o[0]=f2us(v.x); o[1]=f2us(v.y); o[2]=f2us(v.z); o[3]=f2us(v.w);
    *(u16x4*)&out[(size_t)i * 4] = o;
}

// ---------- transpose + convert: in f32 [K][N] -> out bf16 [Npad][K], zero-pad n>=N ----------
__global__ __launch_bounds__(256)
void transpose_cvt(const float* __restrict__ in, u16* __restrict__ out, int K, int N)
{
    __shared__ u16 tile[64][65];
    int k0 = blockIdx.x * 64;
    int n0 = blockIdx.y * 64;
    int t = threadIdx.x;
    #pragma unroll
    for (int q = 0; q < 16; q++) {
        int lin = q * 256 + t;
        int r = lin >> 6, c = lin & 63;     // k=k0+r, n=n0+c
        int n = n0 + c;
        float v = (n < N) ? in[(size_t)(k0 + r) * N + n] : 0.f;
        tile[r][c] = f2us(v);
    }
    __syncthreads();
    #pragma unroll
    for (int q = 0; q < 16; q++) {
        int lin = q * 256 + t;
        int r = lin >> 6, c = lin & 63;     // n=n0+r, k=k0+c
        out[(size_t)(n0 + r) * K + k0 + c] = tile[c][r];
    }
}

// ---------- MFMA bf16 GEMM: C[M,N] = A[M,K] @ Bt[N,K]^T ----------
// BM=BN=128, BK=32, 256 threads (4 waves, 2x2), mfma_f32_16x16x32_bf16.
template<typename TC>
__global__ __launch_bounds__(256)
void gemm_mfma(const u16* __restrict__ A, const u16* __restrict__ Bt,
               TC* __restrict__ C, int M, int N, int K, int ldc)
{
    __shared__ u16 Asm[128][32];   // 8 KB
    __shared__ u16 Bsm[128][32];   // 8 KB
    const int t = threadIdx.x;
    const int lane = t & 63, w = t >> 6;
    const int wr = w >> 1, wc = w & 1;         // wave quadrant (2x2 of 64x64)
    const int lr = lane & 15, kh = lane >> 4;  // frag row/col, k-subblock
    const int m0 = blockIdx.y * 128;
    const int n0 = blockIdx.x * 128;

    f32x4 acc[4][4];
    #pragma unroll
    for (int i = 0; i < 4; i++)
        #pragma unroll
        for (int j = 0; j < 4; j++) acc[i][j] = (f32x4){0.f,0.f,0.f,0.f};

    for (int k0 = 0; k0 < K; k0 += 32) {
        // stage A,B tiles: chunk = 16B = 8 bf16; 512 chunks each; 2 issues per tile
        #pragma unroll
        for (int i = 0; i < 2; i++) {
            int cb = i * 256 + w * 64;             // wave-uniform chunk base
            int chunk = cb + lane;
            int row = chunk >> 2, kb = chunk & 3;
            gload_lds16(&A[(size_t)(m0 + row) * K + k0 + kb * 8], &Asm[0][0] + cb * 8);
            gload_lds16(&Bt[(size_t)(n0 + row) * K + k0 + kb * 8], &Bsm[0][0] + cb * 8);
        }
        __syncthreads();   // drains vmcnt -> LDS tiles ready
        bf16x8 af[4], bf[4];
        #pragma unroll
        for (int i = 0; i < 4; i++)
            af[i] = *(const bf16x8*)&Asm[wr*64 + i*16 + lr][kh*8];
        #pragma unroll
        for (int j = 0; j < 4; j++)
            bf[j] = *(const bf16x8*)&Bsm[wc*64 + j*16 + lr][kh*8];
        #pragma unroll
        for (int i = 0; i < 4; i++)
            #pragma unroll
            for (int j = 0; j < 4; j++)
                acc[i][j] = __builtin_amdgcn_mfma_f32_16x16x32_bf16(af[i], bf[j], acc[i][j], 0, 0, 0);
        __syncthreads();   // all reads done before next-iter staging overwrites
    }
    // epilogue: C[row = (lane>>4)*4+q][col = lane&15] per 16x16 frag
    #pragma unroll
    for (int i = 0; i < 4; i++) {
        #pragma unroll
        for (int j = 0; j < 4; j++) {
            int r = m0 + wr*64 + i*16 + kh*4;
            int cidx = n0 + wc*64 + j*16 + lr;
            #pragma unroll
            for (int q = 0; q < 4; q++) {
                if constexpr (sizeof(TC) == 4) C[(size_t)(r+q)*ldc + cidx] = acc[i][j][q];
                else                           C[(size_t)(r+q)*ldc + cidx] = f2us(acc[i][j][q]);
            }
        }
    }
}

// ---------------- conv1d (K=4) + bias + SiLU, split into x / B / C (bf16 io) ----------------
__global__ __launch_bounds__(256)
void conv_silu(const u16* __restrict__ zx, const float* __restrict__ cw,
               const float* __restrict__ cb, u16* __restrict__ xconv,
               u16* __restrict__ Bbuf, u16* __restrict__ Cbuf)
{
    int idx = blockIdx.x * 256 + threadIdx.x;       // < BATCH*SEQ*CONV_DIM
    int c = idx % CONV_DIM;
    int r = idx / CONV_DIM;                          // b*SEQ + l
    int l = r & (SEQ - 1);
    float y = cb[c];
    #pragma unroll
    for (int k = 0; k < 4; k++) {
        int ls = l + k - 3;
        if (ls >= 0)
            y += us2f(zx[(size_t)(r + k - 3) * LD_ZX + D_INNER + c]) * cw[c*4 + k];
    }
    y = y / (1.f + expf(-y));
    u16 yb = f2us(y);
    if (c < D_INNER)                xconv[(size_t)r * D_INNER + c] = yb;
    else if (c < D_INNER + D_STATE) Bbuf[(size_t)r * D_STATE + (c - D_INNER)] = yb;
    else                            Cbuf[(size_t)r * D_STATE + (c - D_INNER - D_STATE)] = yb;
}

// ---------------- dt softplus + per-chunk cumsum of dA ----------------
__global__ __launch_bounds__(256)
void dt_acs(const u16* __restrict__ zx, const float* __restrict__ Aparam,
            const float* __restrict__ dt_bias, float* __restrict__ dtT,
            float* __restrict__ Acs)
{
    __shared__ float sb[CHUNK];
    int blk = blockIdx.x;                 // b*512 + h*8 + c
    int c = blk & 7, h = (blk >> 3) & 63, b = blk >> 9;
    int t = threadIdx.x;
    int lg = c * CHUNK + t;
    int row = b * SEQ + lg;
    float x = us2f(zx[(size_t)row * LD_ZX + (2*D_INNER + 2*D_STATE) + h]) + dt_bias[h];
    float dt = (x > 20.f) ? x : log1pf(expf(x));
    float v = dt * Aparam[h];
    sb[t] = v; __syncthreads();
    #pragma unroll
    for (int off = 1; off < 256; off <<= 1) {
        float add = (t >= off) ? sb[t - off] : 0.f;
        __syncthreads();
        v += add; sb[t] = v;
        __syncthreads();
    }
    int o = (b * NHEADS + h) * SEQ + lg;
    dtT[o] = dt;
    Acs[o] = v;
}

// ---------------- per-chunk states: states[b,c,h,p,n] (f32 out) ----------------
__global__ __launch_bounds__(256)
void chunk_states(const u16* __restrict__ xconv, const u16* __restrict__ Bbuf,
                  const float* __restrict__ dtT, const float* __restrict__ Acs,
                  float* __restrict__ states)
{
    __shared__ float Bsh[16][128];
    __shared__ float xsh[16][64];
    __shared__ float wsh[16];
    int blk = blockIdx.x;                 // b*512 + c*64 + h
    int h = blk & 63, c = (blk >> 6) & 7, b = blk >> 9;
    int t = threadIdx.x;
    int n = t & 127, p0 = (t >> 7) * 32;
    int bh = b * NHEADS + h;
    float acs_last = Acs[(size_t)bh * SEQ + c * CHUNK + 255];

    float acc[32];
    #pragma unroll
    for (int i = 0; i < 32; i++) acc[i] = 0.f;

    for (int l0 = 0; l0 < CHUNK; l0 += 16) {
        __syncthreads();
        {
            int lrr = t >> 4, nc = (t & 15) * 8;
            u16x8 v = *(const u16x8*)&Bbuf[(size_t)(b*SEQ + c*CHUNK + l0 + lrr) * D_STATE + nc];
            #pragma unroll
            for (int q = 0; q < 8; q++) Bsh[lrr][nc + q] = us2f(v[q]);
        }
        {
            int lrr = t >> 4, pc = (t & 15) * 4;
            u16x4 v = *(const u16x4*)&xconv[(size_t)(b*SEQ + c*CHUNK + l0 + lrr) * D_INNER + h*HEAD_DIM + pc];
            #pragma unroll
            for (int q = 0; q < 4; q++) xsh[lrr][pc + q] = us2f(v[q]);
        }
        if (t < 16) {
            int lgi = c * CHUNK + l0 + t;
            float dt = dtT[(size_t)bh * SEQ + lgi];
            float a  = Acs[(size_t)bh * SEQ + lgi];
            wsh[t] = dt * expf(acs_last - a);
        }
        __syncthreads();
        #pragma unroll
        for (int lrr = 0; lrr < 16; lrr++) {
            float bw = Bsh[lrr][n] * wsh[lrr];
            #pragma unroll
            for (int i = 0; i < 32; i++) acc[i] += bw * xsh[lrr][p0 + i];
        }
    }
    size_t base = ((size_t)((b*NCHUNK + c)*NHEADS + h)) * (HEAD_DIM * D_STATE);
    #pragma unroll
    for (int i = 0; i < 32; i++)
        states[base + (size_t)(p0 + i) * D_STATE + n] = acc[i];
}

// ---------------- inter-chunk recurrence, in place ----------------
__global__ __launch_bounds__(256)
void state_recurrence(float* __restrict__ states, const float* __restrict__ Acs)
{
    int idx = blockIdx.x * 256 + threadIdx.x;  // < BATCH*NHEADS*8192
    int pn = idx & 8191;
    int bh = idx >> 13;
    int b = bh >> 6, h = bh & 63;
    float E = 0.f;
    for (int c = 0; c < NCHUNK; c++) {
        size_t off = ((size_t)((b*NCHUNK + c)*NHEADS + h)) * 8192 + pn;
        float s = states[off];
        states[off] = E;
        float cs = Acs[(size_t)(b*NHEADS + h) * SEQ + c*CHUNK + 255];
        E = expf(cs) * E + s;
    }
}

// ---------------- chunk output: Y = Y_off + D*x + Y_diag (bf16 out) ----------------
__global__ __launch_bounds__(256)
void chunk_output(const u16* __restrict__ xconv, const u16* __restrict__ Bbuf,
                  const u16* __restrict__ Cbuf, const float* __restrict__ dtT,
                  const float* __restrict__ Acs, const float* __restrict__ states,
                  const float* __restrict__ Dparam, u16* __restrict__ Y)
{
    __shared__ float prev[64][128];  // 32 KB
    __shared__ float Bsh[32][128];   // 16 KB
    __shared__ float xsh[32][64];    // 8 KB
    __shared__ float wsh[32];
    __shared__ float ash[32];
    int blk = blockIdx.x;            // b*512 + c*64 + h
    int h = blk & 63, c = (blk >> 6) & 7, b = blk >> 9;
    int t = threadIdx.x;             // = l within chunk
    int bh = b * NHEADS + h;
    int lg = c * CHUNK + t;

    {
        size_t base = ((size_t)((b*NCHUNK + c)*NHEADS + h)) * 8192;
        for (int i = t*4; i < 8192; i += 1024)
            *(float4*)&prev[0][i] = *(const float4*)&states[base + i];
    }
    float cl[128];
    {
        const u16x8* src = (const u16x8*)&Cbuf[(size_t)(b*SEQ + lg) * D_STATE];
        #pragma unroll
        for (int i = 0; i < 16; i++) {
            u16x8 v = src[i];
            #pragma unroll
            for (int q = 0; q < 8; q++) cl[i*8 + q] = us2f(v[q]);
        }
    }
    float acs_l = Acs[(size_t)bh * SEQ + lg];
    float el = expf(acs_l);
    float Dh = Dparam[h];
    float acc[64];
    __syncthreads();
    #pragma unroll
    for (int p = 0; p < 64; p++) {
        float dot = 0.f;
        #pragma unroll
        for (int nn = 0; nn < 128; nn++) dot += cl[nn] * prev[p][nn];
        acc[p] = el * dot;
    }
    {
        const u16x8* xsrc = (const u16x8*)&xconv[(size_t)(b*SEQ + lg) * D_INNER + h*HEAD_DIM];
        #pragma unroll
        for (int p8 = 0; p8 < 8; p8++) {
            u16x8 v = xsrc[p8];
            #pragma unroll
            for (int q = 0; q < 8; q++) acc[p8*8 + q] += Dh * us2f(v[q]);
        }
    }
    for (int st = 0; st < 8; st++) {
        __syncthreads();
        {
            int lrr = t >> 3, nc = (t & 7) * 16;
            const u16* src = &Bbuf[(size_t)(b*SEQ + c*CHUNK + st*32 + lrr) * D_STATE + nc];
            u16x8 v0 = *(const u16x8*)&src[0];
            u16x8 v1 = *(const u16x8*)&src[8];
            #pragma unroll
            for (int q = 0; q < 8; q++) { Bsh[lrr][nc + q] = us2f(v0[q]); Bsh[lrr][nc + 8 + q] = us2f(v1[q]); }
        }
        {
            int lrr = t >> 3, pc = (t & 7) * 8;
            u16x8 v = *(const u16x8*)&xconv[(size_t)(b*SEQ + c*CHUNK + st*32 + lrr) * D_INNER + h*HEAD_DIM + pc];
            #pragma unroll
            for (int q = 0; q < 8; q++) xsh[lrr][pc + q] = us2f(v[q]);
        }
        if (t < 32) {
            int sg = c*CHUNK + st*32 + t;
            wsh[t] = dtT[(size_t)bh * SEQ + sg];
            ash[t] = Acs[(size_t)bh * SEQ + sg];
        }
        __syncthreads();
        if (st*32 > t) continue;
        int smax = t - st*32 + 1; if (smax > 32) smax = 32;
        for (int ss = 0; ss < smax; ss++) {
            float g = 0.f;
            #pragma unroll
            for (int nn = 0; nn < 128; nn++) g += cl[nn] * Bsh[ss][nn];
            float wv = expf(acs_l - ash[ss]) * wsh[ss] * g;
            #pragma unroll
            for (int p = 0; p < 64; p++) acc[p] += wv * xsh[ss][p];
        }
    }
    u16* dst = &Y[(size_t)(b*SEQ + lg) * D_INNER + h*HEAD_DIM];
    #pragma unroll
    for (int p8 = 0; p8 < 8; p8++) {
        u16x8 v;
        #pragma unroll
        for (int q = 0; q < 8; q++) v[q] = f2us(acc[p8*8 + q]);
        *(u16x8*)&dst[p8*8] = v;
    }
}

// ---------------- gated RMSNorm (NGROUPS=1), in place on Y (bf16) ----------------
__global__ __launch_bounds__(256)
void gated_rmsnorm_k(u16* __restrict__ Y, const u16* __restrict__ zx,
                     const float* __restrict__ nw)
{
    __shared__ float xs[D_INNER];
    __shared__ float red[8];
    int row = blockIdx.x;
    int t = threadIdx.x;
    float ss = 0.f;
    for (int i = t*8; i < D_INNER; i += 2048) {
        u16x8 yv = *(const u16x8*)&Y[(size_t)row * D_INNER + i];
        u16x8 zv = *(const u16x8*)&zx[(size_t)row * LD_ZX + i];
        #pragma unroll
        for (int q = 0; q < 8; q++) {
            float x = us2f(yv[q]) * siluf(us2f(zv[q]));
            xs[i + q] = x;
            ss += x * x;
        }
    }
    #pragma unroll
    for (int off = 32; off > 0; off >>= 1) ss += __shfl_down(ss, off);
    int wid = t >> 6, lane = t & 63;
    if (lane == 0) red[wid] = ss;
    __syncthreads();
    if (t == 0) {
        float tot = red[0] + red[1] + red[2] + red[3];
        red[0] = rsqrtf(tot / (float)D_INNER + EPS_RMS);
    }
    __syncthreads();
    float sc = red[0];
    for (int i = t*8; i < D_INNER; i += 2048) {
        u16x8 o;
        #pragma unroll
        for (int q = 0; q < 8; q++) o[q] = f2us(xs[i + q] * sc * nw[i + q]);
        *(u16x8*)&Y[(size_t)row * D_INNER + i] = o;
    }
}

__global__ void ws_fail_k(float* out, float mb){ out[threadIdx.x] = mb; }

// ---------------- launch ----------------
extern "C" void kernel_launch(void* const* d_in, const int* in_sizes, int n_in,
                              void* d_out, int out_size, void* d_ws, size_t ws_size,
                              hipStream_t stream)
{
    const float* hidden  = (const float*)d_in[0];
    const float* W_in    = (const float*)d_in[1];
    const float* conv_w  = (const float*)d_in[2];
    const float* conv_b  = (const float*)d_in[3];
    const float* Aparam  = (const float*)d_in[4];
    const float* Dparam  = (const float*)d_in[5];
    const float* dt_bias = (const float*)d_in[6];
    const float* norm_w  = (const float*)d_in[7];
    const float* W_out   = (const float*)d_in[8];
    float* out = (float*)d_out;

    const int M = BATCH * SEQ;  // 4096

    size_t off = 0;
    char* wsb = (char*)d_ws;
    u16*   zx     = (u16*)  (wsb + off); off += (size_t)M * LD_ZX * 2;               // 70.3 MB
    u16*   xconv  = (u16*)  (wsb + off); off += (size_t)M * D_INNER * 2;             // 33.5 MB
    u16*   Bbuf   = (u16*)  (wsb + off); off += (size_t)M * D_STATE * 2;             // 1 MB
    u16*   Cbuf   = (u16*)  (wsb + off); off += (size_t)M * D_STATE * 2;             // 1 MB
    float* dtT    = (float*)(wsb + off); off += (size_t)BATCH * NHEADS * SEQ * 4;    // 1 MB
    float* Acs    = (float*)(wsb + off); off += (size_t)BATCH * NHEADS * SEQ * 4;    // 1 MB
    float* states = (float*)(wsb + off); off += (size_t)BATCH * NCHUNK * NHEADS * HEAD_DIM * D_STATE * 4; // 33.5 MB
    u16*   Ybuf   = (u16*)  (wsb + off); off += (size_t)M * D_INNER * 2;             // 33.5 MB
    u16*   hbf    = (u16*)  (wsb + off); off += (size_t)M * D_MODEL * 2;             // 16.8 MB
    u16*   WtIn   = (u16*)  (wsb + off); off += (size_t)LD_ZX * D_MODEL * 2;         // 35.1 MB
    u16*   WtOut  = (u16*)  (wsb + off); off += (size_t)D_MODEL * D_INNER * 2;       // 16.8 MB

    if (off > ws_size) {  // scratch too small: absmax will read ~ws_size in MB
        ws_fail_k<<<1, 64, 0, stream>>>(out, (float)(ws_size >> 20));
        return;
    }

    // weight/activation conversions
    cvt_bf16<<<(M * D_MODEL / 4 + 255) / 256, 256, 0, stream>>>(hidden, hbf, M * D_MODEL / 4);
    transpose_cvt<<<dim3(D_MODEL/64, LD_ZX/64), 256, 0, stream>>>(W_in, WtIn, D_MODEL, D_IN_PROJ);
    transpose_cvt<<<dim3(D_INNER/64, D_MODEL/64), 256, 0, stream>>>(W_out, WtOut, D_INNER, D_MODEL);

    // GEMM1: zx[M, LD_ZX] = hbf[M, D_MODEL] @ WtIn^T
    gemm_mfma<u16><<<dim3(LD_ZX/128, M/128), 256, 0, stream>>>(hbf, WtIn, zx, M, LD_ZX, D_MODEL, LD_ZX);

    conv_silu<<<(M * CONV_DIM) / 256, 256, 0, stream>>>(zx, conv_w, conv_b, xconv, Bbuf, Cbuf);
    dt_acs<<<BATCH * NHEADS * NCHUNK, 256, 0, stream>>>(zx, Aparam, dt_bias, dtT, Acs);
    chunk_states<<<BATCH * NCHUNK * NHEADS, 256, 0, stream>>>(xconv, Bbuf, dtT, Acs, states);
    state_recurrence<<<(BATCH * NHEADS * HEAD_DIM * D_STATE) / 256, 256, 0, stream>>>(states, Acs);
    chunk_output<<<BATCH * NCHUNK * NHEADS, 256, 0, stream>>>(xconv, Bbuf, Cbuf, dtT, Acs, states, Dparam, Ybuf);
    gated_rmsnorm_k<<<M, 256, 0, stream>>>(Ybuf, zx, norm_w);

    // GEMM2: out[M, D_MODEL] = Ybuf[M, D_INNER] @ WtOut^T
    gemm_mfma<float><<<dim3(D_MODEL/128, M/128), 256, 0, stream>>>(Ybuf, WtOut, out, M, D_MODEL, D_INNER, D_MODEL);
}

// Round 4
// 707.943 us; speedup vs baseline: 6.1978x; 2.9355x over previous
//
#include <hip/hip_runtime.h>
#include <hip/hip_bf16.h>
#include <math.h>

#define D_MODEL   2048
#define D_INNER   4096
#define NHEADS    64
#define HEAD_DIM  64
#define D_STATE   128
#define CHUNK     256
#define CONV_DIM  (D_INNER + 2*D_STATE)            // 4352
#define D_IN_PROJ (2*D_INNER + 2*D_STATE + NHEADS) // 8512
#define LD_ZX     8576                             // D_IN_PROJ padded to 128
#define BATCH     2
#define SEQ       2048
#define NCHUNK    (SEQ/CHUNK)                      // 8
#define EPS_RMS   1e-5f

typedef unsigned short u16;
typedef __attribute__((ext_vector_type(8))) unsigned short u16x8;
typedef __attribute__((ext_vector_type(4))) unsigned short u16x4;
typedef __attribute__((ext_vector_type(8))) short bf16x8;   // MFMA A/B frag (8 bf16)
typedef __attribute__((ext_vector_type(4))) float f32x4;    // MFMA C/D frag

__device__ __forceinline__ float us2f(u16 u){
    union { unsigned int i; float f; } c; c.i = ((unsigned int)u) << 16; return c.f;
}
__device__ __forceinline__ u16 f2us(float f){
    union { float f; unsigned int i; } c; c.f = f;
    unsigned int r = c.i + 0x7FFFu + ((c.i >> 16) & 1u);
    return (u16)(r >> 16);
}
__device__ __forceinline__ float siluf(float x){ return x / (1.f + expf(-x)); }

__device__ __forceinline__ void gload_lds16(const void* g, void* l) {
    __builtin_amdgcn_global_load_lds((const __attribute__((address_space(1))) void*)g,
                                     (__attribute__((address_space(3))) void*)l, 16, 0, 0);
}

// ---------- elementwise f32 -> bf16 ----------
__global__ __launch_bounds__(256)
void cvt_bf16(const float* __restrict__ in, u16* __restrict__ out, int n4)
{
    int i = blockIdx.x * 256 + threadIdx.x;
    if (i >= n4) return;
    float4 v = *(const float4*)&in[(size_t)i * 4];
    u16x4 o; o[0]=f2us(v.x); o[1]=f2us(v.y); o[2]=f2us(v.z); o[3]=f2us(v.w);
    *(u16x4*)&out[(size_t)i * 4] = o;
}

// ---------- transpose + convert: in f32 [K][N] -> out bf16 [Npad][K], zero-pad n>=N ----------
__global__ __launch_bounds__(256)
void transpose_cvt(const float* __restrict__ in, u16* __restrict__ out, int K, int N)
{
    __shared__ u16 tile[64][65];
    int k0 = blockIdx.x * 64;
    int n0 = blockIdx.y * 64;
    int t = threadIdx.x;
    #pragma unroll
    for (int q = 0; q < 16; q++) {
        int lin = q * 256 + t;
        int r = lin >> 6, c = lin & 63;     // k=k0+r, n=n0+c
        int n = n0 + c;
        float v = (n < N) ? in[(size_t)(k0 + r) * N + n] : 0.f;
        tile[r][c] = f2us(v);
    }
    __syncthreads();
    #pragma unroll
    for (int q = 0; q < 16; q++) {
        int lin = q * 256 + t;
        int r = lin >> 6, c = lin & 63;     // n=n0+r, k=k0+c
        out[(size_t)(n0 + r) * K + k0 + c] = tile[c][r];
    }
}

// ---------- MFMA bf16 GEMM: C[M,N] = A[M,K] @ Bt[N,K]^T ----------
template<typename TC>
__global__ __launch_bounds__(256)
void gemm_mfma(const u16* __restrict__ A, const u16* __restrict__ Bt,
               TC* __restrict__ C, int M, int N, int K, int ldc)
{
    __shared__ u16 Asm[128][32];   // 8 KB
    __shared__ u16 Bsm[128][32];   // 8 KB
    const int t = threadIdx.x;
    const int lane = t & 63, w = t >> 6;
    const int wr = w >> 1, wc = w & 1;
    const int lr = lane & 15, kh = lane >> 4;
    const int m0 = blockIdx.y * 128;
    const int n0 = blockIdx.x * 128;

    f32x4 acc[4][4];
    #pragma unroll
    for (int i = 0; i < 4; i++)
        #pragma unroll
        for (int j = 0; j < 4; j++) acc[i][j] = (f32x4){0.f,0.f,0.f,0.f};

    for (int k0 = 0; k0 < K; k0 += 32) {
        #pragma unroll
        for (int i = 0; i < 2; i++) {
            int cb = i * 256 + w * 64;
            int chunk = cb + lane;
            int row = chunk >> 2, kb = chunk & 3;
            gload_lds16(&A[(size_t)(m0 + row) * K + k0 + kb * 8], &Asm[0][0] + cb * 8);
            gload_lds16(&Bt[(size_t)(n0 + row) * K + k0 + kb * 8], &Bsm[0][0] + cb * 8);
        }
        __syncthreads();
        bf16x8 af[4], bf[4];
        #pragma unroll
        for (int i = 0; i < 4; i++)
            af[i] = *(const bf16x8*)&Asm[wr*64 + i*16 + lr][kh*8];
        #pragma unroll
        for (int j = 0; j < 4; j++)
            bf[j] = *(const bf16x8*)&Bsm[wc*64 + j*16 + lr][kh*8];
        #pragma unroll
        for (int i = 0; i < 4; i++)
            #pragma unroll
            for (int j = 0; j < 4; j++)
                acc[i][j] = __builtin_amdgcn_mfma_f32_16x16x32_bf16(af[i], bf[j], acc[i][j], 0, 0, 0);
        __syncthreads();
    }
    #pragma unroll
    for (int i = 0; i < 4; i++) {
        #pragma unroll
        for (int j = 0; j < 4; j++) {
            int r = m0 + wr*64 + i*16 + kh*4;
            int cidx = n0 + wc*64 + j*16 + lr;
            #pragma unroll
            for (int q = 0; q < 4; q++) {
                if constexpr (sizeof(TC) == 4) C[(size_t)(r+q)*ldc + cidx] = acc[i][j][q];
                else                           C[(size_t)(r+q)*ldc + cidx] = f2us(acc[i][j][q]);
            }
        }
    }
}

// ---------------- conv1d (K=4) + bias + SiLU ----------------
__global__ __launch_bounds__(256)
void conv_silu(const u16* __restrict__ zx, const float* __restrict__ cw,
               const float* __restrict__ cb, u16* __restrict__ xconv,
               u16* __restrict__ Bbuf, u16* __restrict__ Cbuf)
{
    int idx = blockIdx.x * 256 + threadIdx.x;
    int c = idx % CONV_DIM;
    int r = idx / CONV_DIM;
    int l = r & (SEQ - 1);
    float y = cb[c];
    #pragma unroll
    for (int k = 0; k < 4; k++) {
        int ls = l + k - 3;
        if (ls >= 0)
            y += us2f(zx[(size_t)(r + k - 3) * LD_ZX + D_INNER + c]) * cw[c*4 + k];
    }
    y = y / (1.f + expf(-y));
    u16 yb = f2us(y);
    if (c < D_INNER)                xconv[(size_t)r * D_INNER + c] = yb;
    else if (c < D_INNER + D_STATE) Bbuf[(size_t)r * D_STATE + (c - D_INNER)] = yb;
    else                            Cbuf[(size_t)r * D_STATE + (c - D_INNER - D_STATE)] = yb;
}

// ---------------- dt softplus + per-chunk cumsum ----------------
__global__ __launch_bounds__(256)
void dt_acs(const u16* __restrict__ zx, const float* __restrict__ Aparam,
            const float* __restrict__ dt_bias, float* __restrict__ dtT,
            float* __restrict__ Acs)
{
    __shared__ float sb[CHUNK];
    int blk = blockIdx.x;
    int c = blk & 7, h = (blk >> 3) & 63, b = blk >> 9;
    int t = threadIdx.x;
    int lg = c * CHUNK + t;
    int row = b * SEQ + lg;
    float x = us2f(zx[(size_t)row * LD_ZX + (2*D_INNER + 2*D_STATE) + h]) + dt_bias[h];
    float dt = (x > 20.f) ? x : log1pf(expf(x));
    float v = dt * Aparam[h];
    sb[t] = v; __syncthreads();
    #pragma unroll
    for (int off = 1; off < 256; off <<= 1) {
        float add = (t >= off) ? sb[t - off] : 0.f;
        __syncthreads();
        v += add; sb[t] = v;
        __syncthreads();
    }
    int o = (b * NHEADS + h) * SEQ + lg;
    dtT[o] = dt;
    Acs[o] = v;
}

// ---------------- per-chunk states (unchanged) ----------------
__global__ __launch_bounds__(256)
void chunk_states(const u16* __restrict__ xconv, const u16* __restrict__ Bbuf,
                  const float* __restrict__ dtT, const float* __restrict__ Acs,
                  float* __restrict__ states)
{
    __shared__ float Bsh[16][128];
    __shared__ float xsh[16][64];
    __shared__ float wsh[16];
    int blk = blockIdx.x;
    int h = blk & 63, c = (blk >> 6) & 7, b = blk >> 9;
    int t = threadIdx.x;
    int n = t & 127, p0 = (t >> 7) * 32;
    int bh = b * NHEADS + h;
    float acs_last = Acs[(size_t)bh * SEQ + c * CHUNK + 255];

    float acc[32];
    #pragma unroll
    for (int i = 0; i < 32; i++) acc[i] = 0.f;

    for (int l0 = 0; l0 < CHUNK; l0 += 16) {
        __syncthreads();
        {
            int lrr = t >> 4, nc = (t & 15) * 8;
            u16x8 v = *(const u16x8*)&Bbuf[(size_t)(b*SEQ + c*CHUNK + l0 + lrr) * D_STATE + nc];
            #pragma unroll
            for (int q = 0; q < 8; q++) Bsh[lrr][nc + q] = us2f(v[q]);
        }
        {
            int lrr = t >> 4, pc = (t & 15) * 4;
            u16x4 v = *(const u16x4*)&xconv[(size_t)(b*SEQ + c*CHUNK + l0 + lrr) * D_INNER + h*HEAD_DIM + pc];
            #pragma unroll
            for (int q = 0; q < 4; q++) xsh[lrr][pc + q] = us2f(v[q]);
        }
        if (t < 16) {
            int lgi = c * CHUNK + l0 + t;
            float dt = dtT[(size_t)bh * SEQ + lgi];
            float a  = Acs[(size_t)bh * SEQ + lgi];
            wsh[t] = dt * expf(acs_last - a);
        }
        __syncthreads();
        #pragma unroll
        for (int lrr = 0; lrr < 16; lrr++) {
            float bw = Bsh[lrr][n] * wsh[lrr];
            #pragma unroll
            for (int i = 0; i < 32; i++) acc[i] += bw * xsh[lrr][p0 + i];
        }
    }
    size_t base = ((size_t)((b*NCHUNK + c)*NHEADS + h)) * (HEAD_DIM * D_STATE);
    #pragma unroll
    for (int i = 0; i < 32; i++)
        states[base + (size_t)(p0 + i) * D_STATE + n] = acc[i];
}

// ---------------- inter-chunk recurrence ----------------
__global__ __launch_bounds__(256)
void state_recurrence(float* __restrict__ states, const float* __restrict__ Acs)
{
    int idx = blockIdx.x * 256 + threadIdx.x;
    int pn = idx & 8191;
    int bh = idx >> 13;
    int b = bh >> 6, h = bh & 63;
    float E = 0.f;
    for (int c = 0; c < NCHUNK; c++) {
        size_t off = ((size_t)((b*NCHUNK + c)*NHEADS + h)) * 8192 + pn;
        float s = states[off];
        states[off] = E;
        float cs = Acs[(size_t)(b*NHEADS + h) * SEQ + c*CHUNK + 255];
        E = expf(cs) * E + s;
    }
}

// ---------------- chunk output, MFMA version ----------------
// Per block (b,c,h): Y[l][p] = sum_{s<=l} (C_l.B_s) exp(acs_l-acs_s) dt_s x_s[p]
//                             + exp(acs_l) * (C_l . prev[p][:])  + D_h x_l[p]
// 4 waves; wave w owns l-rows [w*64, w*64+64). C kept as reg A-frags.
__global__ __launch_bounds__(256, 1)
void chunk_output_mfma(const u16* __restrict__ xconv, const u16* __restrict__ Bbuf,
                       const u16* __restrict__ Cbuf, const float* __restrict__ dtT,
                       const float* __restrict__ Acs, const float* __restrict__ states,
                       const float* __restrict__ Dparam, u16* __restrict__ Y)
{
    __shared__ u16 Bsm[64][130];       // B tile [s][n]; later prev [p][n]   16.6 KB
    __shared__ u16 xt[64][66];         // x^T tile [p][s]                     8.4 KB
    __shared__ u16 Pt[4][64][66];      // per-wave P [l_local][s_local]      33.8 KB
    __shared__ float acs_sh[CHUNK];
    __shared__ float dt_sh[CHUNK];

    const int blk = blockIdx.x;                 // b*512 + c*64 + h
    const int h = blk & 63, c = (blk >> 6) & 7, b = blk >> 9;
    const int t = threadIdx.x;
    const int lane = t & 63, w = t >> 6;
    const int lr = lane & 15, kh = lane >> 4;
    const int bh = b * NHEADS + h;
    const size_t rowbase = (size_t)(b * SEQ + c * CHUNK);

    acs_sh[t] = Acs[(size_t)bh * SEQ + c * CHUNK + t];
    dt_sh[t]  = dtT[(size_t)bh * SEQ + c * CHUNK + t];

    // C A-fragments in registers: row l = w*64 + i*16 + lr, k n = kk*32 + kh*8
    bf16x8 af[4][4];
    #pragma unroll
    for (int i = 0; i < 4; i++)
        #pragma unroll
        for (int kk = 0; kk < 4; kk++)
            af[i][kk] = *(const bf16x8*)&Cbuf[(rowbase + w*64 + i*16 + lr) * D_STATE + kk*32 + kh*8];

    f32x4 yacc[4][4];
    #pragma unroll
    for (int i = 0; i < 4; i++)
        #pragma unroll
        for (int j = 0; j < 4; j++) yacc[i][j] = (f32x4){0.f,0.f,0.f,0.f};

    for (int st = 0; st < 4; st++) {
        __syncthreads();   // prior-tile LDS reads done before restaging
        {   // stage B tile: thread -> row sr, 32-col group
            int sr = t >> 2, cg = (t & 3) * 32;
            const u16* src = &Bbuf[(rowbase + st*64 + sr) * D_STATE + cg];
            #pragma unroll
            for (int q = 0; q < 4; q++)
                *(u16x8*)&Bsm[sr][cg + q*8] = *(const u16x8*)&src[q*8];
        }
        {   // stage x^T tile: thread -> col s, 16-row (p) group
            int s = t & 63, pg = t >> 6;
            const u16* src = &xconv[(rowbase + st*64 + s) * D_INNER + h*HEAD_DIM + pg*16];
            u16x8 v0 = *(const u16x8*)&src[0];
            u16x8 v1 = *(const u16x8*)&src[8];
            #pragma unroll
            for (int q = 0; q < 8; q++) { xt[pg*16 + q][s] = v0[q]; xt[pg*16 + 8 + q][s] = v1[q]; }
        }
        __syncthreads();

        // S = C @ B^T  (64 l x 64 s per wave, K=128)
        f32x4 sacc[4][4];
        #pragma unroll
        for (int i = 0; i < 4; i++)
            #pragma unroll
            for (int js = 0; js < 4; js++) sacc[i][js] = (f32x4){0.f,0.f,0.f,0.f};
        #pragma unroll
        for (int kk = 0; kk < 4; kk++) {
            bf16x8 bfr[4];
            #pragma unroll
            for (int js = 0; js < 4; js++)
                bfr[js] = *(const bf16x8*)&Bsm[js*16 + lr][kk*32 + kh*8];
            #pragma unroll
            for (int i = 0; i < 4; i++)
                #pragma unroll
                for (int js = 0; js < 4; js++)
                    sacc[i][js] = __builtin_amdgcn_mfma_f32_16x16x32_bf16(af[i][kk], bfr[js], sacc[i][js], 0, 0, 0);
        }
        // mask + scale + write P (wave-private LDS)
        #pragma unroll
        for (int i = 0; i < 4; i++) {
            #pragma unroll
            for (int js = 0; js < 4; js++) {
                int sl = js*16 + lr;
                int sg = st*64 + sl;
                float as = acs_sh[sg], ds = dt_sh[sg];
                #pragma unroll
                for (int q = 0; q < 4; q++) {
                    int l = w*64 + i*16 + kh*4 + q;
                    float arg = fminf(acs_sh[l] - as, 0.f);
                    float fac = (sg <= l) ? expf(arg) * ds : 0.f;
                    Pt[w][i*16 + kh*4 + q][sl] = f2us(sacc[i][js][q] * fac);
                }
            }
        }
        // Y += P @ x^T  (K = 64)
        #pragma unroll
        for (int kk2 = 0; kk2 < 2; kk2++) {
            bf16x8 pa[4], xb[4];
            #pragma unroll
            for (int i = 0; i < 4; i++)
                pa[i] = *(const bf16x8*)&Pt[w][i*16 + lr][kk2*32 + kh*8];
            #pragma unroll
            for (int j = 0; j < 4; j++)
                xb[j] = *(const bf16x8*)&xt[j*16 + lr][kk2*32 + kh*8];
            #pragma unroll
            for (int i = 0; i < 4; i++)
                #pragma unroll
                for (int j = 0; j < 4; j++)
                    yacc[i][j] = __builtin_amdgcn_mfma_f32_16x16x32_bf16(pa[i], xb[j], yacc[i][j], 0, 0, 0);
        }
    }

    // Y_off: stage prev (f32 -> bf16) into Bsm area, then Y += (e .* C) @ prev^T
    __syncthreads();
    {
        int p = t >> 2, ng = (t & 3) * 32;
        const float* src = &states[((size_t)((b*NCHUNK + c)*NHEADS + h)) * 8192 + (size_t)p * 128 + ng];
        #pragma unroll
        for (int q = 0; q < 4; q++) {
            float4 v0 = *(const float4*)&src[q*8];
            float4 v1 = *(const float4*)&src[q*8 + 4];
            u16x8 o;
            o[0]=f2us(v0.x); o[1]=f2us(v0.y); o[2]=f2us(v0.z); o[3]=f2us(v0.w);
            o[4]=f2us(v1.x); o[5]=f2us(v1.y); o[6]=f2us(v1.z); o[7]=f2us(v1.w);
            *(u16x8*)&Bsm[p][ng + q*8] = o;
        }
    }
    __syncthreads();
    {
        float el[4];
        #pragma unroll
        for (int i = 0; i < 4; i++) el[i] = expf(acs_sh[w*64 + i*16 + lr]);  // A-frag row = lr
        #pragma unroll
        for (int kk = 0; kk < 4; kk++) {
            bf16x8 pvf[4];
            #pragma unroll
            for (int j = 0; j < 4; j++)
                pvf[j] = *(const bf16x8*)&Bsm[j*16 + lr][kk*32 + kh*8];   // prev[p][n]
            #pragma unroll
            for (int i = 0; i < 4; i++) {
                bf16x8 ae;
                #pragma unroll
                for (int e = 0; e < 8; e++)
                    ae[e] = (short)f2us(us2f((u16)af[i][kk][e]) * el[i]);
                #pragma unroll
                for (int j = 0; j < 4; j++)
                    yacc[i][j] = __builtin_amdgcn_mfma_f32_16x16x32_bf16(ae, pvf[j], yacc[i][j], 0, 0, 0);
            }
        }
    }

    // epilogue: += D*x, store bf16
    float Dh = Dparam[h];
    #pragma unroll
    for (int i = 0; i < 4; i++) {
        #pragma unroll
        for (int j = 0; j < 4; j++) {
            #pragma unroll
            for (int q = 0; q < 4; q++) {
                int l = w*64 + i*16 + kh*4 + q;
                int p = j*16 + lr;
                size_t o = (rowbase + l) * D_INNER + h*HEAD_DIM + p;
                float v = yacc[i][j][q] + Dh * us2f(xconv[o]);
                Y[o] = f2us(v);
            }
        }
    }
}

// ---------------- gated RMSNorm ----------------
__global__ __launch_bounds__(256)
void gated_rmsnorm_k(u16* __restrict__ Y, const u16* __restrict__ zx,
                     const float* __restrict__ nw)
{
    __shared__ float xs[D_INNER];
    __shared__ float red[8];
    int row = blockIdx.x;
    int t = threadIdx.x;
    float ss = 0.f;
    for (int i = t*8; i < D_INNER; i += 2048) {
        u16x8 yv = *(const u16x8*)&Y[(size_t)row * D_INNER + i];
        u16x8 zv = *(const u16x8*)&zx[(size_t)row * LD_ZX + i];
        #pragma unroll
        for (int q = 0; q < 8; q++) {
            float x = us2f(yv[q]) * siluf(us2f(zv[q]));
            xs[i + q] = x;
            ss += x * x;
        }
    }
    #pragma unroll
    for (int off = 32; off > 0; off >>= 1) ss += __shfl_down(ss, off);
    int wid = t >> 6, lane = t & 63;
    if (lane == 0) red[wid] = ss;
    __syncthreads();
    if (t == 0) {
        float tot = red[0] + red[1] + red[2] + red[3];
        red[0] = rsqrtf(tot / (float)D_INNER + EPS_RMS);
    }
    __syncthreads();
    float sc = red[0];
    for (int i = t*8; i < D_INNER; i += 2048) {
        u16x8 o;
        #pragma unroll
        for (int q = 0; q < 8; q++) o[q] = f2us(xs[i + q] * sc * nw[i + q]);
        *(u16x8*)&Y[(size_t)row * D_INNER + i] = o;
    }
}

__global__ void ws_fail_k(float* out, float mb){ out[threadIdx.x] = mb; }

// ---------------- launch ----------------
extern "C" void kernel_launch(void* const* d_in, const int* in_sizes, int n_in,
                              void* d_out, int out_size, void* d_ws, size_t ws_size,
                              hipStream_t stream)
{
    const float* hidden  = (const float*)d_in[0];
    const float* W_in    = (const float*)d_in[1];
    const float* conv_w  = (const float*)d_in[2];
    const float* conv_b  = (const float*)d_in[3];
    const float* Aparam  = (const float*)d_in[4];
    const float* Dparam  = (const float*)d_in[5];
    const float* dt_bias = (const float*)d_in[6];
    const float* norm_w  = (const float*)d_in[7];
    const float* W_out   = (const float*)d_in[8];
    float* out = (float*)d_out;

    const int M = BATCH * SEQ;  // 4096

    size_t off = 0;
    char* wsb = (char*)d_ws;
    u16*   zx     = (u16*)  (wsb + off); off += (size_t)M * LD_ZX * 2;
    u16*   xconv  = (u16*)  (wsb + off); off += (size_t)M * D_INNER * 2;
    u16*   Bbuf   = (u16*)  (wsb + off); off += (size_t)M * D_STATE * 2;
    u16*   Cbuf   = (u16*)  (wsb + off); off += (size_t)M * D_STATE * 2;
    float* dtT    = (float*)(wsb + off); off += (size_t)BATCH * NHEADS * SEQ * 4;
    float* Acs    = (float*)(wsb + off); off += (size_t)BATCH * NHEADS * SEQ * 4;
    float* states = (float*)(wsb + off); off += (size_t)BATCH * NCHUNK * NHEADS * HEAD_DIM * D_STATE * 4;
    u16*   Ybuf   = (u16*)  (wsb + off); off += (size_t)M * D_INNER * 2;
    u16*   hbf    = (u16*)  (wsb + off); off += (size_t)M * D_MODEL * 2;
    u16*   WtIn   = (u16*)  (wsb + off); off += (size_t)LD_ZX * D_MODEL * 2;
    u16*   WtOut  = (u16*)  (wsb + off); off += (size_t)D_MODEL * D_INNER * 2;

    if (off > ws_size) {
        ws_fail_k<<<1, 64, 0, stream>>>(out, (float)(ws_size >> 20));
        return;
    }

    cvt_bf16<<<(M * D_MODEL / 4 + 255) / 256, 256, 0, stream>>>(hidden, hbf, M * D_MODEL / 4);
    transpose_cvt<<<dim3(D_MODEL/64, LD_ZX/64), 256, 0, stream>>>(W_in, WtIn, D_MODEL, D_IN_PROJ);
    transpose_cvt<<<dim3(D_INNER/64, D_MODEL/64), 256, 0, stream>>>(W_out, WtOut, D_INNER, D_MODEL);

    gemm_mfma<u16><<<dim3(LD_ZX/128, M/128), 256, 0, stream>>>(hbf, WtIn, zx, M, LD_ZX, D_MODEL, LD_ZX);

    conv_silu<<<(M * CONV_DIM) / 256, 256, 0, stream>>>(zx, conv_w, conv_b, xconv, Bbuf, Cbuf);
    dt_acs<<<BATCH * NHEADS * NCHUNK, 256, 0, stream>>>(zx, Aparam, dt_bias, dtT, Acs);
    chunk_states<<<BATCH * NCHUNK * NHEADS, 256, 0, stream>>>(xconv, Bbuf, dtT, Acs, states);
    state_recurrence<<<(BATCH * NHEADS * HEAD_DIM * D_STATE) / 256, 256, 0, stream>>>(states, Acs);
    chunk_output_mfma<<<BATCH * NCHUNK * NHEADS, 256, 0, stream>>>(xconv, Bbuf, Cbuf, dtT, Acs, states, Dparam, Ybuf);
    gated_rmsnorm_k<<<M, 256, 0, stream>>>(Ybuf, zx, norm_w);

    gemm_mfma<float><<<dim3(D_MODEL/128, M/128), 256, 0, stream>>>(Ybuf, WtOut, out, M, D_MODEL, D_INNER, D_MODEL);
}

// Round 5
// 614.383 us; speedup vs baseline: 7.1416x; 1.1523x over previous
//
#include <hip/hip_runtime.h>
#include <hip/hip_bf16.h>
#include <math.h>

#define D_MODEL   2048
#define D_INNER   4096
#define NHEADS    64
#define HEAD_DIM  64
#define D_STATE   128
#define CHUNK     256
#define CONV_DIM  (D_INNER + 2*D_STATE)            // 4352
#define D_IN_PROJ (2*D_INNER + 2*D_STATE + NHEADS) // 8512
#define LD_ZX     8576                             // D_IN_PROJ padded to 128
#define BATCH     2
#define SEQ       2048
#define NCHUNK    (SEQ/CHUNK)                      // 8
#define EPS_RMS   1e-5f

typedef unsigned short u16;
typedef __attribute__((ext_vector_type(8))) unsigned short u16x8;
typedef __attribute__((ext_vector_type(4))) unsigned short u16x4;
typedef __attribute__((ext_vector_type(8))) short bf16x8;   // MFMA A/B frag (8 bf16)
typedef __attribute__((ext_vector_type(4))) float f32x4;    // MFMA C/D frag

__device__ __forceinline__ float us2f(u16 u){
    union { unsigned int i; float f; } c; c.i = ((unsigned int)u) << 16; return c.f;
}
__device__ __forceinline__ u16 f2us(float f){
    union { float f; unsigned int i; } c; c.f = f;
    unsigned int r = c.i + 0x7FFFu + ((c.i >> 16) & 1u);
    return (u16)(r >> 16);
}
__device__ __forceinline__ float siluf(float x){ return x / (1.f + expf(-x)); }

__device__ __forceinline__ void gload_lds16(const void* g, void* l) {
    __builtin_amdgcn_global_load_lds((const __attribute__((address_space(1))) void*)g,
                                     (__attribute__((address_space(3))) void*)l, 16, 0, 0);
}

// ---------- elementwise f32 -> bf16 ----------
__global__ __launch_bounds__(256)
void cvt_bf16(const float* __restrict__ in, u16* __restrict__ out, int n4)
{
    int i = blockIdx.x * 256 + threadIdx.x;
    if (i >= n4) return;
    float4 v = *(const float4*)&in[(size_t)i * 4];
    u16x4 o; o[0]=f2us(v.x); o[1]=f2us(v.y); o[2]=f2us(v.z); o[3]=f2us(v.w);
    *(u16x4*)&out[(size_t)i * 4] = o;
}

// ---------- transpose + convert: in f32 [K][N] -> out bf16 [Npad][K], zero-pad n>=N ----------
__global__ __launch_bounds__(256)
void transpose_cvt(const float* __restrict__ in, u16* __restrict__ out, int K, int N)
{
    __shared__ u16 tile[64][65];
    int k0 = blockIdx.x * 64;
    int n0 = blockIdx.y * 64;
    int t = threadIdx.x;
    #pragma unroll
    for (int q = 0; q < 16; q++) {
        int lin = q * 256 + t;
        int r = lin >> 6, c = lin & 63;
        int n = n0 + c;
        float v = (n < N) ? in[(size_t)(k0 + r) * N + n] : 0.f;
        tile[r][c] = f2us(v);
    }
    __syncthreads();
    #pragma unroll
    for (int q = 0; q < 16; q++) {
        int lin = q * 256 + t;
        int r = lin >> 6, c = lin & 63;
        out[(size_t)(n0 + r) * K + k0 + c] = tile[c][r];
    }
}

// ---------- MFMA bf16 GEMM: C[M,N] = A[M,K] @ Bt[N,K]^T, XCD-swizzled blocks ----------
template<typename TC>
__global__ __launch_bounds__(256)
void gemm_mfma(const u16* __restrict__ A, const u16* __restrict__ Bt,
               TC* __restrict__ C, int M, int N, int K, int ldc)
{
    __shared__ u16 Asm[128][32];   // 8 KB
    __shared__ u16 Bsm[128][32];   // 8 KB
    const int t = threadIdx.x;
    const int lane = t & 63, w = t >> 6;
    const int wr = w >> 1, wc = w & 1;
    const int lr = lane & 15, kh = lane >> 4;

    // bijective XCD swizzle (m204): contiguous wgid chunk per XCD
    const int nwg = gridDim.x * gridDim.y;
    const int orig = blockIdx.y * gridDim.x + blockIdx.x;
    const int qq = nwg >> 3, r8 = nwg & 7;
    const int xcd = orig & 7, loc = orig >> 3;
    const int wgid = (xcd < r8 ? xcd*(qq+1) : r8*(qq+1) + (xcd-r8)*qq) + loc;
    const int m0 = (wgid / gridDim.x) * 128;
    const int n0 = (wgid % gridDim.x) * 128;

    f32x4 acc[4][4];
    #pragma unroll
    for (int i = 0; i < 4; i++)
        #pragma unroll
        for (int j = 0; j < 4; j++) acc[i][j] = (f32x4){0.f,0.f,0.f,0.f};

    for (int k0 = 0; k0 < K; k0 += 32) {
        #pragma unroll
        for (int i = 0; i < 2; i++) {
            int cb = i * 256 + w * 64;
            int chunk = cb + lane;
            int row = chunk >> 2, kb = chunk & 3;
            gload_lds16(&A[(size_t)(m0 + row) * K + k0 + kb * 8], &Asm[0][0] + cb * 8);
            gload_lds16(&Bt[(size_t)(n0 + row) * K + k0 + kb * 8], &Bsm[0][0] + cb * 8);
        }
        __syncthreads();
        bf16x8 af[4], bf[4];
        #pragma unroll
        for (int i = 0; i < 4; i++)
            af[i] = *(const bf16x8*)&Asm[wr*64 + i*16 + lr][kh*8];
        #pragma unroll
        for (int j = 0; j < 4; j++)
            bf[j] = *(const bf16x8*)&Bsm[wc*64 + j*16 + lr][kh*8];
        #pragma unroll
        for (int i = 0; i < 4; i++)
            #pragma unroll
            for (int j = 0; j < 4; j++)
                acc[i][j] = __builtin_amdgcn_mfma_f32_16x16x32_bf16(af[i], bf[j], acc[i][j], 0, 0, 0);
        __syncthreads();
    }
    #pragma unroll
    for (int i = 0; i < 4; i++) {
        #pragma unroll
        for (int j = 0; j < 4; j++) {
            int r = m0 + wr*64 + i*16 + kh*4;
            int cidx = n0 + wc*64 + j*16 + lr;
            #pragma unroll
            for (int q = 0; q < 4; q++) {
                if constexpr (sizeof(TC) == 4) C[(size_t)(r+q)*ldc + cidx] = acc[i][j][q];
                else                           C[(size_t)(r+q)*ldc + cidx] = f2us(acc[i][j][q]);
            }
        }
    }
}

// ---------------- conv1d (K=4) + bias + SiLU, 8 channels/thread ----------------
__global__ __launch_bounds__(256)
void conv_silu(const u16* __restrict__ zx, const float* __restrict__ cw,
               const float* __restrict__ cb, u16* __restrict__ xconv,
               u16* __restrict__ Bbuf, u16* __restrict__ Cbuf)
{
    int idx = blockIdx.x * 256 + threadIdx.x;        // < M * (CONV_DIM/8)
    int cg = idx % (CONV_DIM / 8);
    int r  = idx / (CONV_DIM / 8);
    int c0 = cg * 8;
    int l  = r & (SEQ - 1);

    float y[8];
    {
        float4 b0 = *(const float4*)&cb[c0];
        float4 b1 = *(const float4*)&cb[c0 + 4];
        y[0]=b0.x; y[1]=b0.y; y[2]=b0.z; y[3]=b0.w;
        y[4]=b1.x; y[5]=b1.y; y[6]=b1.z; y[7]=b1.w;
    }
    float cwf[8][4];
    #pragma unroll
    for (int e = 0; e < 8; e++) {
        float4 v = *(const float4*)&cw[(c0 + e) * 4];
        cwf[e][0]=v.x; cwf[e][1]=v.y; cwf[e][2]=v.z; cwf[e][3]=v.w;
    }
    #pragma unroll
    for (int k = 0; k < 4; k++) {
        if (l + k - 3 >= 0) {
            u16x8 v = *(const u16x8*)&zx[(size_t)(r + k - 3) * LD_ZX + D_INNER + c0];
            #pragma unroll
            for (int e = 0; e < 8; e++) y[e] += us2f(v[e]) * cwf[e][k];
        }
    }
    u16x8 o;
    #pragma unroll
    for (int e = 0; e < 8; e++) {
        float s = y[e] / (1.f + expf(-y[e]));
        o[e] = f2us(s);
    }
    if (c0 < D_INNER)                *(u16x8*)&xconv[(size_t)r * D_INNER + c0] = o;
    else if (c0 < D_INNER + D_STATE) *(u16x8*)&Bbuf[(size_t)r * D_STATE + (c0 - D_INNER)] = o;
    else                             *(u16x8*)&Cbuf[(size_t)r * D_STATE + (c0 - D_INNER - D_STATE)] = o;
}

// ---------------- dt softplus + per-chunk cumsum ----------------
__global__ __launch_bounds__(256)
void dt_acs(const u16* __restrict__ zx, const float* __restrict__ Aparam,
            const float* __restrict__ dt_bias, float* __restrict__ dtT,
            float* __restrict__ Acs)
{
    __shared__ float sb[CHUNK];
    int blk = blockIdx.x;
    int c = blk & 7, h = (blk >> 3) & 63, b = blk >> 9;
    int t = threadIdx.x;
    int lg = c * CHUNK + t;
    int row = b * SEQ + lg;
    float x = us2f(zx[(size_t)row * LD_ZX + (2*D_INNER + 2*D_STATE) + h]) + dt_bias[h];
    float dt = (x > 20.f) ? x : log1pf(expf(x));
    float v = dt * Aparam[h];
    sb[t] = v; __syncthreads();
    #pragma unroll
    for (int off = 1; off < 256; off <<= 1) {
        float add = (t >= off) ? sb[t - off] : 0.f;
        __syncthreads();
        v += add; sb[t] = v;
        __syncthreads();
    }
    int o = (b * NHEADS + h) * SEQ + lg;
    dtT[o] = dt;
    Acs[o] = v;
}

// ---------------- per-chunk states via MFMA: states[p][n] = sum_l x_l[p] * (w_l B_l[n]) ----------------
// 4 waves (2x2 over p-half x n-half); K = 256 in 4 tiles of 64.
__global__ __launch_bounds__(256)
void chunk_states_mfma(const u16* __restrict__ xconv, const u16* __restrict__ Bbuf,
                       const float* __restrict__ dtT, const float* __restrict__ Acs,
                       float* __restrict__ states)
{
    __shared__ u16 Btsh[128][72];   // (w*B)^T [n][l]  18.4 KB (72: 16B-aligned rows, conflict-free)
    __shared__ u16 xtsh[64][72];    // x^T [p][l]       9.2 KB
    __shared__ float acs_sh[CHUNK];
    __shared__ float dt_sh[CHUNK];

    const int blk = blockIdx.x;                 // b*512 + c*64 + h
    const int h = blk & 63, c = (blk >> 6) & 7, b = blk >> 9;
    const int t = threadIdx.x;
    const int lane = t & 63, w = t >> 6;
    const int wr = w >> 1, wc = w & 1;
    const int lr = lane & 15, kh = lane >> 4;
    const int bh = b * NHEADS + h;
    const size_t rowbase = (size_t)(b * SEQ + c * CHUNK);

    acs_sh[t] = Acs[(size_t)bh * SEQ + c * CHUNK + t];
    dt_sh[t]  = dtT[(size_t)bh * SEQ + c * CHUNK + t];
    __syncthreads();
    const float acs_last = acs_sh[CHUNK - 1];

    f32x4 acc[2][4];
    #pragma unroll
    for (int i = 0; i < 2; i++)
        #pragma unroll
        for (int j = 0; j < 4; j++) acc[i][j] = (f32x4){0.f,0.f,0.f,0.f};

    for (int lt = 0; lt < 4; lt++) {
        __syncthreads();   // prior-tile LDS reads done
        const int s = t & 63;
        const int sg = lt * 64 + s;
        const float wgt = dt_sh[sg] * expf(acs_last - acs_sh[sg]);
        {   // (w*B)^T staging: thread covers 32 n's at column s
            int ng = (t >> 6) * 32;
            const u16* src = &Bbuf[(rowbase + sg) * D_STATE + ng];
            #pragma unroll
            for (int q = 0; q < 4; q++) {
                u16x8 v = *(const u16x8*)&src[q * 8];
                #pragma unroll
                for (int e = 0; e < 8; e++)
                    Btsh[ng + q*8 + e][s] = f2us(us2f(v[e]) * wgt);
            }
        }
        {   // x^T staging: thread covers 16 p's at column s
            int pg = (t >> 6) * 16;
            const u16* src = &xconv[(rowbase + sg) * D_INNER + h * HEAD_DIM + pg];
            u16x8 v0 = *(const u16x8*)&src[0];
            u16x8 v1 = *(const u16x8*)&src[8];
            #pragma unroll
            for (int e = 0; e < 8; e++) { xtsh[pg + e][s] = v0[e]; xtsh[pg + 8 + e][s] = v1[e]; }
        }
        __syncthreads();
        #pragma unroll
        for (int kk = 0; kk < 2; kk++) {
            bf16x8 af[2], bf[4];
            #pragma unroll
            for (int i = 0; i < 2; i++)
                af[i] = *(const bf16x8*)&xtsh[wr*32 + i*16 + lr][kk*32 + kh*8];
            #pragma unroll
            for (int j = 0; j < 4; j++)
                bf[j] = *(const bf16x8*)&Btsh[wc*64 + j*16 + lr][kk*32 + kh*8];
            #pragma unroll
            for (int i = 0; i < 2; i++)
                #pragma unroll
                for (int j = 0; j < 4; j++)
                    acc[i][j] = __builtin_amdgcn_mfma_f32_16x16x32_bf16(af[i], bf[j], acc[i][j], 0, 0, 0);
        }
    }
    size_t base = ((size_t)((b*NCHUNK + c)*NHEADS + h)) * (HEAD_DIM * D_STATE);
    #pragma unroll
    for (int i = 0; i < 2; i++) {
        #pragma unroll
        for (int j = 0; j < 4; j++) {
            int p = wr*32 + i*16 + kh*4;
            int n = wc*64 + j*16 + lr;
            #pragma unroll
            for (int q = 0; q < 4; q++)
                states[base + (size_t)(p + q) * D_STATE + n] = acc[i][j][q];
        }
    }
}

// ---------------- inter-chunk recurrence ----------------
__global__ __launch_bounds__(256)
void state_recurrence(float* __restrict__ states, const float* __restrict__ Acs)
{
    int idx = blockIdx.x * 256 + threadIdx.x;
    int pn = idx & 8191;
    int bh = idx >> 13;
    int b = bh >> 6, h = bh & 63;
    float E = 0.f;
    for (int c = 0; c < NCHUNK; c++) {
        size_t off = ((size_t)((b*NCHUNK + c)*NHEADS + h)) * 8192 + pn;
        float s = states[off];
        states[off] = E;
        float cs = Acs[(size_t)(b*NHEADS + h) * SEQ + c*CHUNK + 255];
        E = expf(cs) * E + s;
    }
}

// ---------------- chunk output, MFMA (unchanged from round 4) ----------------
__global__ __launch_bounds__(256, 1)
void chunk_output_mfma(const u16* __restrict__ xconv, const u16* __restrict__ Bbuf,
                       const u16* __restrict__ Cbuf, const float* __restrict__ dtT,
                       const float* __restrict__ Acs, const float* __restrict__ states,
                       const float* __restrict__ Dparam, u16* __restrict__ Y)
{
    __shared__ u16 Bsm[64][130];
    __shared__ u16 xt[64][66];
    __shared__ u16 Pt[4][64][66];
    __shared__ float acs_sh[CHUNK];
    __shared__ float dt_sh[CHUNK];

    const int blk = blockIdx.x;
    const int h = blk & 63, c = (blk >> 6) & 7, b = blk >> 9;
    const int t = threadIdx.x;
    const int lane = t & 63, w = t >> 6;
    const int lr = lane & 15, kh = lane >> 4;
    const int bh = b * NHEADS + h;
    const size_t rowbase = (size_t)(b * SEQ + c * CHUNK);

    acs_sh[t] = Acs[(size_t)bh * SEQ + c * CHUNK + t];
    dt_sh[t]  = dtT[(size_t)bh * SEQ + c * CHUNK + t];

    bf16x8 af[4][4];
    #pragma unroll
    for (int i = 0; i < 4; i++)
        #pragma unroll
        for (int kk = 0; kk < 4; kk++)
            af[i][kk] = *(const bf16x8*)&Cbuf[(rowbase + w*64 + i*16 + lr) * D_STATE + kk*32 + kh*8];

    f32x4 yacc[4][4];
    #pragma unroll
    for (int i = 0; i < 4; i++)
        #pragma unroll
        for (int j = 0; j < 4; j++) yacc[i][j] = (f32x4){0.f,0.f,0.f,0.f};

    for (int st = 0; st < 4; st++) {
        __syncthreads();
        {
            int sr = t >> 2, cg = (t & 3) * 32;
            const u16* src = &Bbuf[(rowbase + st*64 + sr) * D_STATE + cg];
            #pragma unroll
            for (int q = 0; q < 4; q++)
                *(u16x8*)&Bsm[sr][cg + q*8] = *(const u16x8*)&src[q*8];
        }
        {
            int s = t & 63, pg = t >> 6;
            const u16* src = &xconv[(rowbase + st*64 + s) * D_INNER + h*HEAD_DIM + pg*16];
            u16x8 v0 = *(const u16x8*)&src[0];
            u16x8 v1 = *(const u16x8*)&src[8];
            #pragma unroll
            for (int q = 0; q < 8; q++) { xt[pg*16 + q][s] = v0[q]; xt[pg*16 + 8 + q][s] = v1[q]; }
        }
        __syncthreads();

        f32x4 sacc[4][4];
        #pragma unroll
        for (int i = 0; i < 4; i++)
            #pragma unroll
            for (int js = 0; js < 4; js++) sacc[i][js] = (f32x4){0.f,0.f,0.f,0.f};
        #pragma unroll
        for (int kk = 0; kk < 4; kk++) {
            bf16x8 bfr[4];
            #pragma unroll
            for (int js = 0; js < 4; js++)
                bfr[js] = *(const bf16x8*)&Bsm[js*16 + lr][kk*32 + kh*8];
            #pragma unroll
            for (int i = 0; i < 4; i++)
                #pragma unroll
                for (int js = 0; js < 4; js++)
                    sacc[i][js] = __builtin_amdgcn_mfma_f32_16x16x32_bf16(af[i][kk], bfr[js], sacc[i][js], 0, 0, 0);
        }
        #pragma unroll
        for (int i = 0; i < 4; i++) {
            #pragma unroll
            for (int js = 0; js < 4; js++) {
                int sl = js*16 + lr;
                int sg = st*64 + sl;
                float as = acs_sh[sg], ds = dt_sh[sg];
                #pragma unroll
                for (int q = 0; q < 4; q++) {
                    int l = w*64 + i*16 + kh*4 + q;
                    float arg = fminf(acs_sh[l] - as, 0.f);
                    float fac = (sg <= l) ? expf(arg) * ds : 0.f;
                    Pt[w][i*16 + kh*4 + q][sl] = f2us(sacc[i][js][q] * fac);
                }
            }
        }
        #pragma unroll
        for (int kk2 = 0; kk2 < 2; kk2++) {
            bf16x8 pa[4], xb[4];
            #pragma unroll
            for (int i = 0; i < 4; i++)
                pa[i] = *(const bf16x8*)&Pt[w][i*16 + lr][kk2*32 + kh*8];
            #pragma unroll
            for (int j = 0; j < 4; j++)
                xb[j] = *(const bf16x8*)&xt[j*16 + lr][kk2*32 + kh*8];
            #pragma unroll
            for (int i = 0; i < 4; i++)
                #pragma unroll
                for (int j = 0; j < 4; j++)
                    yacc[i][j] = __builtin_amdgcn_mfma_f32_16x16x32_bf16(pa[i], xb[j], yacc[i][j], 0, 0, 0);
        }
    }

    __syncthreads();
    {
        int p = t >> 2, ng = (t & 3) * 32;
        const float* src = &states[((size_t)((b*NCHUNK + c)*NHEADS + h)) * 8192 + (size_t)p * 128 + ng];
        #pragma unroll
        for (int q = 0; q < 4; q++) {
            float4 v0 = *(const float4*)&src[q*8];
            float4 v1 = *(const float4*)&src[q*8 + 4];
            u16x8 o;
            o[0]=f2us(v0.x); o[1]=f2us(v0.y); o[2]=f2us(v0.z); o[3]=f2us(v0.w);
            o[4]=f2us(v1.x); o[5]=f2us(v1.y); o[6]=f2us(v1.z); o[7]=f2us(v1.w);
            *(u16x8*)&Bsm[p][ng + q*8] = o;
        }
    }
    __syncthreads();
    {
        float el[4];
        #pragma unroll
        for (int i = 0; i < 4; i++) el[i] = expf(acs_sh[w*64 + i*16 + lr]);
        #pragma unroll
        for (int kk = 0; kk < 4; kk++) {
            bf16x8 pvf[4];
            #pragma unroll
            for (int j = 0; j < 4; j++)
                pvf[j] = *(const bf16x8*)&Bsm[j*16 + lr][kk*32 + kh*8];
            #pragma unroll
            for (int i = 0; i < 4; i++) {
                bf16x8 ae;
                #pragma unroll
                for (int e = 0; e < 8; e++)
                    ae[e] = (short)f2us(us2f((u16)af[i][kk][e]) * el[i]);
                #pragma unroll
                for (int j = 0; j < 4; j++)
                    yacc[i][j] = __builtin_amdgcn_mfma_f32_16x16x32_bf16(ae, pvf[j], yacc[i][j], 0, 0, 0);
            }
        }
    }

    float Dh = Dparam[h];
    #pragma unroll
    for (int i = 0; i < 4; i++) {
        #pragma unroll
        for (int j = 0; j < 4; j++) {
            #pragma unroll
            for (int q = 0; q < 4; q++) {
                int l = w*64 + i*16 + kh*4 + q;
                int p = j*16 + lr;
                size_t o = (rowbase + l) * D_INNER + h*HEAD_DIM + p;
                float v = yacc[i][j][q] + Dh * us2f(xconv[o]);
                Y[o] = f2us(v);
            }
        }
    }
}

// ---------------- gated RMSNorm ----------------
__global__ __launch_bounds__(256)
void gated_rmsnorm_k(u16* __restrict__ Y, const u16* __restrict__ zx,
                     const float* __restrict__ nw)
{
    __shared__ float xs[D_INNER];
    __shared__ float red[8];
    int row = blockIdx.x;
    int t = threadIdx.x;
    float ss = 0.f;
    for (int i = t*8; i < D_INNER; i += 2048) {
        u16x8 yv = *(const u16x8*)&Y[(size_t)row * D_INNER + i];
        u16x8 zv = *(const u16x8*)&zx[(size_t)row * LD_ZX + i];
        #pragma unroll
        for (int q = 0; q < 8; q++) {
            float x = us2f(yv[q]) * siluf(us2f(zv[q]));
            xs[i + q] = x;
            ss += x * x;
        }
    }
    #pragma unroll
    for (int off = 32; off > 0; off >>= 1) ss += __shfl_down(ss, off);
    int wid = t >> 6, lane = t & 63;
    if (lane == 0) red[wid] = ss;
    __syncthreads();
    if (t == 0) {
        float tot = red[0] + red[1] + red[2] + red[3];
        red[0] = rsqrtf(tot / (float)D_INNER + EPS_RMS);
    }
    __syncthreads();
    float sc = red[0];
    for (int i = t*8; i < D_INNER; i += 2048) {
        u16x8 o;
        #pragma unroll
        for (int q = 0; q < 8; q++) o[q] = f2us(xs[i + q] * sc * nw[i + q]);
        *(u16x8*)&Y[(size_t)row * D_INNER + i] = o;
    }
}

__global__ void ws_fail_k(float* out, float mb){ out[threadIdx.x] = mb; }

// ---------------- launch ----------------
extern "C" void kernel_launch(void* const* d_in, const int* in_sizes, int n_in,
                              void* d_out, int out_size, void* d_ws, size_t ws_size,
                              hipStream_t stream)
{
    const float* hidden  = (const float*)d_in[0];
    const float* W_in    = (const float*)d_in[1];
    const float* conv_w  = (const float*)d_in[2];
    const float* conv_b  = (const float*)d_in[3];
    const float* Aparam  = (const float*)d_in[4];
    const float* Dparam  = (const float*)d_in[5];
    const float* dt_bias = (const float*)d_in[6];
    const float* norm_w  = (const float*)d_in[7];
    const float* W_out   = (const float*)d_in[8];
    float* out = (float*)d_out;

    const int M = BATCH * SEQ;  // 4096

    size_t off = 0;
    char* wsb = (char*)d_ws;
    u16*   zx     = (u16*)  (wsb + off); off += (size_t)M * LD_ZX * 2;
    u16*   xconv  = (u16*)  (wsb + off); off += (size_t)M * D_INNER * 2;
    u16*   Bbuf   = (u16*)  (wsb + off); off += (size_t)M * D_STATE * 2;
    u16*   Cbuf   = (u16*)  (wsb + off); off += (size_t)M * D_STATE * 2;
    float* dtT    = (float*)(wsb + off); off += (size_t)BATCH * NHEADS * SEQ * 4;
    float* Acs    = (float*)(wsb + off); off += (size_t)BATCH * NHEADS * SEQ * 4;
    float* states = (float*)(wsb + off); off += (size_t)BATCH * NCHUNK * NHEADS * HEAD_DIM * D_STATE * 4;
    u16*   Ybuf   = (u16*)  (wsb + off); off += (size_t)M * D_INNER * 2;
    u16*   hbf    = (u16*)  (wsb + off); off += (size_t)M * D_MODEL * 2;
    u16*   WtIn   = (u16*)  (wsb + off); off += (size_t)LD_ZX * D_MODEL * 2;
    u16*   WtOut  = (u16*)  (wsb + off); off += (size_t)D_MODEL * D_INNER * 2;

    if (off > ws_size) {
        ws_fail_k<<<1, 64, 0, stream>>>(out, (float)(ws_size >> 20));
        return;
    }

    cvt_bf16<<<(M * D_MODEL / 4 + 255) / 256, 256, 0, stream>>>(hidden, hbf, M * D_MODEL / 4);
    transpose_cvt<<<dim3(D_MODEL/64, LD_ZX/64), 256, 0, stream>>>(W_in, WtIn, D_MODEL, D_IN_PROJ);
    transpose_cvt<<<dim3(D_INNER/64, D_MODEL/64), 256, 0, stream>>>(W_out, WtOut, D_INNER, D_MODEL);

    gemm_mfma<u16><<<dim3(LD_ZX/128, M/128), 256, 0, stream>>>(hbf, WtIn, zx, M, LD_ZX, D_MODEL, LD_ZX);

    conv_silu<<<(M * CONV_DIM / 8) / 256, 256, 0, stream>>>(zx, conv_w, conv_b, xconv, Bbuf, Cbuf);
    dt_acs<<<BATCH * NHEADS * NCHUNK, 256, 0, stream>>>(zx, Aparam, dt_bias, dtT, Acs);
    chunk_states_mfma<<<BATCH * NCHUNK * NHEADS, 256, 0, stream>>>(xconv, Bbuf, dtT, Acs, states);
    state_recurrence<<<(BATCH * NHEADS * HEAD_DIM * D_STATE) / 256, 256, 0, stream>>>(states, Acs);
    chunk_output_mfma<<<BATCH * NCHUNK * NHEADS, 256, 0, stream>>>(xconv, Bbuf, Cbuf, dtT, Acs, states, Dparam, Ybuf);
    gated_rmsnorm_k<<<M, 256, 0, stream>>>(Ybuf, zx, norm_w);

    gemm_mfma<float><<<dim3(D_MODEL/128, M/128), 256, 0, stream>>>(Ybuf, WtOut, out, M, D_MODEL, D_INNER, D_MODEL);
}